// Round 1
// 405.148 us; speedup vs baseline: 1.1325x; 1.1325x over previous
//
#include <hip/hip_runtime.h>
#include <cmath>

// Problem constants: S=16384, IN_DIM=1024, D=6400, BINS=20
#define S_DIM 16384
#define K_DIM 1024
#define D_DIM 6400
#define NBINS 20
#define HSTRIDE 21   // shist column stride (pad 20->21: spreads banks)

using half_t = _Float16;
using half8  = __attribute__((ext_vector_type(8))) _Float16;
using f32x4  = __attribute__((ext_vector_type(4))) float;

// ---------------- fp32 -> fp16 convert (both arrays, one launch) ----------
// Each thread: 8 floats (2x float4 in) -> 8 halves (16B out).
__global__ void cvt_f32_f16(const float* __restrict__ a, half_t* __restrict__ da, int n8a,
                            const float* __restrict__ b, half_t* __restrict__ db, int n8b) {
  int i = blockIdx.x * blockDim.x + threadIdx.x;
  const float* s; half_t* d; int idx;
  if (i < n8a) { s = a; d = da; idx = i; }
  else { idx = i - n8a; if (idx >= n8b) return; s = b; d = db; }
  float4 v0 = ((const float4*)s)[idx * 2];
  float4 v1 = ((const float4*)s)[idx * 2 + 1];
  half8 h = { (half_t)v0.x, (half_t)v0.y, (half_t)v0.z, (half_t)v0.w,
              (half_t)v1.x, (half_t)v1.y, (half_t)v1.z, (half_t)v1.w };
  ((half8*)d)[idx] = h;
}

// Raw barrier / counted waitcnt (no compiler vmcnt(0) drain at barriers).
#define VMWAIT(N) __asm__ volatile("s_waitcnt vmcnt(" #N ")" ::: "memory")
#define BAR()     __asm__ volatile("s_barrier" ::: "memory")
#define SP1()     __builtin_amdgcn_s_setprio(1)
#define SP0()     __builtin_amdgcn_s_setprio(0)

#define GLL(SRC, DST) __builtin_amdgcn_global_load_lds(                      \
    (const __attribute__((address_space(1))) void*)(SRC),                    \
    (__attribute__((address_space(3))) void*)(DST), 16, 0, 0)

// ---------------- fused GEMM + histogram, 256x256 tile, 8-wave 4-phase ----
// 512 threads = 8 waves (2M x 4N); per-wave C = 128x64; BK=64; dbuf LDS.
// Per K-tile: 4 phases x {ds_read frag subtile; stage 1 half-tile (2 DMA);
// barrier; setprio(1); 16 MFMA; setprio(0); [vmcnt(4) at ph3]; barrier}.
// Stage schedule (half-tiles, lead 6): ph0->B.h0(t+1) ph1->B.h1(t+1)
// ph2->A.h0(t+2) ph3->A.h1(t+2).  Restage of every region is barrier-
// separated from its last ds_read (A.h0 read ph0/restaged ph2; A.h1 read
// ph2/restaged ph3; B halves of buf[(t+1)&1] last read at t-1.ph0/ph1).
// vmcnt(4) at ph3 retires everything except A(t+2) -> tile t+1 resident
// in LDS before its ph0 reads, 2 half-tiles stay in flight (never 0).
// LDS swizzle: 16B chunk c within a 128B row stored at c ^ (row&7)
// (applied on the GLOBAL source so global_load_lds dest stays linear;
// ds_read applies the same XOR -> 2-way banks, free).
__global__ __launch_bounds__(512, 2) void gemm_hist256(
    const half_t* __restrict__ xh, const half_t* __restrict__ wh,
    const float* __restrict__ mins, const float* __restrict__ maxs,
    int* __restrict__ ghist)
{
  __shared__ __align__(16) char ldsA[65536];   // 2 bufs x 256 rows x 128 B
  __shared__ __align__(16) char ldsB[65536];
  __shared__ int shist[256 * HSTRIDE];         // 21.5 KB

  const int t    = threadIdx.x;
  const int lane = t & 63;
  const int wv   = t >> 6;
  const int wm   = wv >> 2;          // 0..1
  const int wn   = wv & 3;           // 0..3
  const int l16  = lane & 15;
  const int quad = lane >> 4;

  // XCD-aware bijective swizzle: 1600 blocks = 8 XCDs x 200
  const int bid = blockIdx.x;
  const int wg  = (bid & 7) * 200 + (bid >> 3);
  const int ct  = wg / 64;                 // 0..24 col-tiles
  const int rt  = wg - ct * 64;            // 0..63 row-tiles
  const int colBase = ct * 256;
  const int rowBase = rt * 256;

  for (int i = t; i < 256 * HSTRIDE; i += 512) shist[i] = 0;

  // histogram params: this lane's 4 columns (col = wn*64 + nf*16 + l16)
  float mn[4], mx[4], inv[4];
  int lcol[4];
#pragma unroll
  for (int nf = 0; nf < 4; ++nf) {
    int lc = wn * 64 + nf * 16 + l16;
    lcol[nf] = lc;
    float a = mins[colBase + lc], b = maxs[colBase + lc];
    mn[nf] = a; mx[nf] = b;
    inv[nf] = (float)NBINS / (b - a);
  }

  // LDS fragment-read addressing (bytes). Row stride 128 B, 8x16B chunks.
  const int aRB = (wm * 128 + l16) * 128;
  const int bRB = (wn * 64 + l16) * 128;
  int xk[2];
  xk[0] = ((0 * 4 + quad) ^ (lane & 7)) * 16;   // k-slice 0 chunk, swizzled
  xk[1] = ((1 * 4 + quad) ^ (lane & 7)) * 16;   // k-slice 1 chunk, swizzled

  // Staging: thread t owns linear LDS slot s=t (+512), fetches the global
  // chunk whose swizzled destination is that slot (pre-swizzled source).
  const int r0 = t >> 3, c0 = t & 7;
  const int gOff = r0 * K_DIM + ((c0 ^ (r0 & 7)) * 8);  // elements; j=1 adds 64*K
  const int dOfs = t * 16;                              // bytes;   j=1 adds 8192

  const half_t* baseA = xh + (size_t)rowBase * K_DIM;
  const half_t* baseB = wh + (size_t)colBase * K_DIM;

  auto stageA = [&](int tau, int hf) {
    const half_t* src = baseA + (size_t)hf * (128 * K_DIM) + tau * 64 + gOff;
    char* dst = ldsA + (tau & 1) * 32768 + hf * 16384 + dOfs;
    GLL(src, dst);
    GLL(src + 64 * K_DIM, dst + 8192);
  };
  auto stageB = [&](int tau, int hf) {
    const half_t* src = baseB + (size_t)hf * (128 * K_DIM) + tau * 64 + gOff;
    char* dst = ldsB + (tau & 1) * 32768 + hf * 16384 + dOfs;
    GLL(src, dst);
    GLL(src + 64 * K_DIM, dst + 8192);
  };

  f32x4 acc[8][4];
#pragma unroll
  for (int m = 0; m < 8; ++m)
#pragma unroll
    for (int n = 0; n < 4; ++n) acc[m][n] = (f32x4){0.f, 0.f, 0.f, 0.f};

  half8 aF[4][2], bF[4][2];

  // prologue: h0..h5 = A0(0),A1(0),B0(0),B1(0),A0(1),A1(1); tile0 must land.
  stageA(0, 0); stageA(0, 1); stageB(0, 0); stageB(0, 1); stageA(1, 0); stageA(1, 1);
  VMWAIT(4); BAR();

#define LOAD_A(MH, BUFO)                                                     \
  _Pragma("unroll") for (int fm = 0; fm < 4; ++fm)                           \
  _Pragma("unroll") for (int ks = 0; ks < 2; ++ks)                           \
    aF[fm][ks] = *(const half8*)(ldsA + (BUFO) + aRB + ((MH)*4+fm)*2048 + xk[ks]);

#define LOAD_B(NH, BUFO)                                                     \
  _Pragma("unroll") for (int fn = 0; fn < 2; ++fn)                           \
  _Pragma("unroll") for (int ks = 0; ks < 2; ++ks)                           \
    bF[(NH)*2+fn][ks] = *(const half8*)(ldsB + (BUFO) + bRB + ((NH)*2+fn)*2048 + xk[ks]);

#define MFMA_Q(MH, NH)                                                       \
  _Pragma("unroll") for (int fm = 0; fm < 4; ++fm)                           \
  _Pragma("unroll") for (int fn = 0; fn < 2; ++fn)                           \
  _Pragma("unroll") for (int ks = 0; ks < 2; ++ks)                           \
    acc[(MH)*4+fm][(NH)*2+fn] = __builtin_amdgcn_mfma_f32_16x16x32_f16(      \
        aF[fm][ks], bF[(NH)*2+fn][ks], acc[(MH)*4+fm][(NH)*2+fn], 0, 0, 0);

#define TILE(T, S0, S1, S2, S3, VMACT)                                       \
  {                                                                          \
    const int bufo = ((T) & 1) * 32768;                                      \
    LOAD_A(0, bufo); LOAD_B(0, bufo);                                        \
    if (S0) stageB((T) + 1, 0);                                              \
    BAR(); SP1(); MFMA_Q(0, 0); SP0(); BAR();                                \
    LOAD_B(1, bufo);                                                         \
    if (S1) stageB((T) + 1, 1);                                              \
    BAR(); SP1(); MFMA_Q(0, 1); SP0(); BAR();                                \
    LOAD_A(1, bufo);                                                         \
    if (S2) stageA((T) + 2, 0);                                              \
    BAR(); SP1(); MFMA_Q(1, 1); SP0(); BAR();                                \
    if (S3) stageA((T) + 2, 1);                                              \
    BAR(); SP1(); MFMA_Q(1, 0); SP0(); VMACT; BAR();                         \
  }

  for (int tt = 0; tt < 14; tt += 2) {
    TILE(tt,     1, 1, 1, 1, VMWAIT(4));
    TILE(tt + 1, 1, 1, 1, 1, VMWAIT(4));
  }
  TILE(14, 1, 1, 0, 0, VMWAIT(0));   // stage B(15) only; drain pipeline
  TILE(15, 0, 0, 0, 0, (void)0);     // compute last tile, no staging

  // Epilogue: bin this block's 256x256 projections (128 values/thread).
  // torch.histc semantics: count iff min<=v<=max; v==max -> last bin.
#pragma unroll
  for (int nf = 0; nf < 4; ++nf) {
    const float a = mn[nf], b = mx[nf], sc = inv[nf];
    int* colHist = &shist[lcol[nf] * HSTRIDE];
#pragma unroll
    for (int mf = 0; mf < 8; ++mf) {
#pragma unroll
      for (int r = 0; r < 4; ++r) {
        float v = acc[mf][nf][r];
        if (v >= a && v <= b) {
          int bin = (int)((v - a) * sc);          // (v-a)>=0 -> trunc==floor
          bin = bin > NBINS - 1 ? NBINS - 1 : bin;
          atomicAdd(&colHist[bin], 1);
        }
      }
    }
  }
  __syncthreads();
  for (int i = t; i < 256 * NBINS; i += 512) {
    int col = i / NBINS, bin = i - col * NBINS;
    int v = shist[col * HSTRIDE + bin];
    if (v) atomicAdd(&ghist[colBase * NBINS + i], v);
  }
}

// ---------------- fallback (no workspace): fp32-staged 128x128 tile -------
__global__ __launch_bounds__(256) void gemm_hist_fb(
    const float* __restrict__ xf, const float* __restrict__ wf,
    const float* __restrict__ mins, const float* __restrict__ maxs,
    int* __restrict__ ghist)
{
  __shared__ __align__(16) half_t ldsA[4096];
  __shared__ __align__(16) half_t ldsB[4096];
  __shared__ int shist[128 * HSTRIDE];

  const int t     = threadIdx.x;
  const int lane  = t & 63;
  const int wv    = t >> 6;
  const int waveM = wv >> 1;
  const int waveN = wv & 1;
  const int l16   = lane & 15;
  const int quad  = lane >> 4;
  const int colBase = blockIdx.x * 128;

  for (int i = t; i < 128 * HSTRIDE; i += 256) shist[i] = 0;

  float mn[4], mx[4], inv[4];
  int lcol[4];
#pragma unroll
  for (int nt = 0; nt < 4; ++nt) {
    int lc = waveN * 64 + nt * 16 + l16;
    lcol[nt] = lc;
    float a = mins[colBase + lc], b = maxs[colBase + lc];
    mn[nt] = a; mx[nt] = b;
    inv[nt] = (float)NBINS / (b - a);
  }

  int aOff[4], bOff[4];
#pragma unroll
  for (int mt = 0; mt < 4; ++mt) {
    int m = waveM * 64 + mt * 16 + l16;
    aOff[mt] = (m * 4 + (quad ^ ((m >> 1) & 3))) * 8;
  }
#pragma unroll
  for (int nt = 0; nt < 4; ++nt) {
    int n = waveN * 64 + nt * 16 + l16;
    bOff[nt] = (n * 4 + (quad ^ ((n >> 1) & 3))) * 8;
  }

  for (int rt = blockIdx.y; rt < S_DIM / 128; rt += gridDim.y) {
    const int rowBase = rt * 128;
    f32x4 acc[4][4];
#pragma unroll
    for (int mt = 0; mt < 4; ++mt)
#pragma unroll
      for (int nt = 0; nt < 4; ++nt) acc[mt][nt] = (f32x4){0.f, 0.f, 0.f, 0.f};

    for (int kt = 0; kt < K_DIM; kt += 32) {
      __syncthreads();
#pragma unroll
      for (int i = 0; i < 2; ++i) {
        const int seg = t + i * 256;
        const int row = seg >> 2;
        const int kch = (seg & 3) ^ ((row >> 1) & 3);
        const float* ga = xf + (size_t)(rowBase + row) * K_DIM + kt + kch * 8;
        float4 v0 = ((const float4*)ga)[0];
        float4 v1 = ((const float4*)ga)[1];
        half8 h = { (half_t)v0.x, (half_t)v0.y, (half_t)v0.z, (half_t)v0.w,
                    (half_t)v1.x, (half_t)v1.y, (half_t)v1.z, (half_t)v1.w };
        *(half8*)&ldsA[seg * 8] = h;
        const float* gb = wf + (size_t)(colBase + row) * K_DIM + kt + kch * 8;
        float4 u0 = ((const float4*)gb)[0];
        float4 u1 = ((const float4*)gb)[1];
        half8 g = { (half_t)u0.x, (half_t)u0.y, (half_t)u0.z, (half_t)u0.w,
                    (half_t)u1.x, (half_t)u1.y, (half_t)u1.z, (half_t)u1.w };
        *(half8*)&ldsB[seg * 8] = g;
      }
      __syncthreads();
      {
        half8 aFf[4], bFf[4];
#pragma unroll
        for (int mt = 0; mt < 4; ++mt) aFf[mt] = *(const half8*)&ldsA[aOff[mt]];
#pragma unroll
        for (int nt = 0; nt < 4; ++nt) bFf[nt] = *(const half8*)&ldsB[bOff[nt]];
#pragma unroll
        for (int mt = 0; mt < 4; ++mt)
#pragma unroll
          for (int nt = 0; nt < 4; ++nt)
            acc[mt][nt] = __builtin_amdgcn_mfma_f32_16x16x32_f16(
                aFf[mt], bFf[nt], acc[mt][nt], 0, 0, 0);
      }
    }

#pragma unroll
    for (int nt = 0; nt < 4; ++nt) {
      const float a = mn[nt], b = mx[nt], sc = inv[nt];
      int* colHist = &shist[lcol[nt] * HSTRIDE];
#pragma unroll
      for (int mt = 0; mt < 4; ++mt) {
#pragma unroll
        for (int r = 0; r < 4; ++r) {
          float v = acc[mt][nt][r];
          if (v >= a && v <= b) {
            int bin = (int)((v - a) * sc);
            bin = bin > NBINS - 1 ? NBINS - 1 : bin;
            atomicAdd(&colHist[bin], 1);
          }
        }
      }
    }
  }

  __syncthreads();
  for (int i = t; i < 128 * NBINS; i += 256) {
    int col = i / NBINS, bin = i - col * NBINS;
    int v = shist[col * HSTRIDE + bin];
    if (v) atomicAdd(&ghist[colBase * NBINS + i], v);
  }
}

// ---------------- L2 normalize per group of 20 bins (in place) ------------
__global__ void normalize_kernel(const int* __restrict__ hist, float* __restrict__ out) {
  int g = blockIdx.x * blockDim.x + threadIdx.x;
  if (g >= D_DIM) return;
  const int base = g * NBINS;
  float v[NBINS];
  float ss = 0.f;
#pragma unroll
  for (int i = 0; i < NBINS; ++i) { v[i] = (float)hist[base + i]; ss += v[i] * v[i]; }
  float sc = 1.0f / fmaxf(sqrtf(ss), 1e-12f);
#pragma unroll
  for (int i = 0; i < NBINS; ++i) out[base + i] = v[i] * sc;
}

extern "C" void kernel_launch(void* const* d_in, const int* in_sizes, int n_in,
                              void* d_out, int out_size, void* d_ws, size_t ws_size,
                              hipStream_t stream) {
  const float* x    = (const float*)d_in[0];
  const float* W    = (const float*)d_in[1];
  const float* mins = (const float*)d_in[2];
  const float* maxs = (const float*)d_in[3];
  float* out = (float*)d_out;

  // d_out doubles as the int histogram accumulator; zero it (re-poisoned 0xAA).
  hipMemsetAsync(d_out, 0, (size_t)out_size * sizeof(float), stream);

  const size_t xh_elems = (size_t)S_DIM * K_DIM;
  const size_t wh_elems = (size_t)D_DIM * K_DIM;
  const size_t need = (xh_elems + wh_elems) * sizeof(half_t);

  if (ws_size >= need) {
    half_t* xh = (half_t*)d_ws;
    half_t* wh = xh + xh_elems;
    int n8x = (int)(xh_elems / 8), n8w = (int)(wh_elems / 8);
    int tot = n8x + n8w;
    cvt_f32_f16<<<(tot + 255) / 256, 256, 0, stream>>>(x, xh, n8x, W, wh, n8w);
    gemm_hist256<<<dim3(1600), 512, 0, stream>>>(xh, wh, mins, maxs, (int*)d_out);
  } else {
    gemm_hist_fb<<<dim3(D_DIM / 128, 64), 256, 0, stream>>>(
        x, W, mins, maxs, (int*)d_out);
  }

  normalize_kernel<<<(D_DIM + 255) / 256, 256, 0, stream>>>((int*)d_out, out);
}